// Round 1
// baseline (5998.020 us; speedup 1.0000x reference)
//
#include <hip/hip_runtime.h>

// ---------------------------------------------------------------------------
// Seq2SeqAttentionDecoder — fp32 correctness baseline (round 1)
//
// Phases:
//  1. init h0/h1 from hidden_state
//  2. gather xs = emb[X]                     (t-major rows r = t*B+b)
//  3. keys = enc @ Wk^T                      (tiled GEMM)
//  4. gi0x = xs @ W_ih0[:,H:]^T + b_ih0      (tiled GEMM, hoisted out of scan)
//  5. 64 sequential steps:
//       q     = h1 @ Wq^T                    (split-K skinny GEMM -> partials)
//       scores= tanh(q + keys)·wv, masked    (fuses q-partial reduce)
//       ctx   = softmax(scores) @ enc
//       gi0c  = ctx @ W_ih0[:,:H]^T, gh0 = h0 @ W_hh0^T   (split-K, z-fused)
//       h0    = GRU(gi0x[t]+gi0c, gh0+b_hh0, h0)          (reduces partials)
//       gi1   = h0 @ W_ih1^T,      gh1 = h1 @ W_hh1^T
//       h1    = GRU(gi1+b_ih1, gh1+b_hh1, h1); outs[t] = h1
//  6. logits = outs @ W_out^T + b_out, written with [T*B]->[B,T] permute
//
// Determinism: no atomics; every ws region read is written first each call.
// Workspace: ~68.6 MB fp32.
// ---------------------------------------------------------------------------

#define BB 32
#define TT 64
#define SS 128
#define HH 1024
#define EE 512
#define VV 32000
#define H3 3072
#define NEGV (-1000000.0f)
#define KS 8          // split-K factor for recurrent GEMMs

// ---------- init h0/h1 ----------
__global__ __launch_bounds__(256) void k_init_h(const float* __restrict__ hid,
                                                float* __restrict__ h0,
                                                float* __restrict__ h1) {
  int i = blockIdx.x * 256 + threadIdx.x;      // grid covers exactly 2*B*H
  if (i < BB * HH) h0[i] = hid[i];
  else             h1[i - BB * HH] = hid[i];
}

// ---------- gather xs[r= t*B+b][e] = emb[X[b][t]][e] ----------
__global__ __launch_bounds__(256) void k_gather(const int* __restrict__ X,
                                                const float* __restrict__ emb,
                                                float* __restrict__ xs) {
  int idx = blockIdx.x * 256 + threadIdx.x;    // over T*B*E/4 float4s
  int r = idx >> 7, c4 = (idx & 127) << 2;
  int td = r >> 5, b = r & 31;
  int tok = X[b * TT + td];
  *(float4*)(xs + (size_t)r * EE + c4) =
      *(const float4*)(emb + (size_t)tok * EE + c4);
}

// ---------- tiled GEMM: C[M,N] = A[M,K] @ W[N,K]^T (+bias) ----------
// 128x128 tile, Ktile=16, 256 threads, 8x8 per thread.
// permuteBT: output row r = t*B+b is written to logits[(b*T + t)*N + n].
__global__ __launch_bounds__(256) void k_gemm_tiled(
    const float* __restrict__ A, int lda,
    const float* __restrict__ W, int ldw,
    const float* __restrict__ bias,
    float* __restrict__ C, int M, int N, int K, int permuteBT) {
  __shared__ float As[16][132];   // [k][m], pad 4 -> conflict-free stores
  __shared__ float Ws[16][132];   // [k][n]
  const int m0 = blockIdx.y * 128, n0 = blockIdx.x * 128;
  const int t = threadIdx.x;
  const int tm = t >> 4, tn = t & 15;
  float acc[8][8] = {};
  for (int k0 = 0; k0 < K; k0 += 16) {
#pragma unroll
    for (int qq = 0; qq < 2; ++qq) {
      int f = t * 2 + qq;                 // 0..511
      int row = f >> 2, c4 = (f & 3) << 2;
      float4 va = *(const float4*)(A + (size_t)(m0 + row) * lda + k0 + c4);
      As[c4 + 0][row] = va.x; As[c4 + 1][row] = va.y;
      As[c4 + 2][row] = va.z; As[c4 + 3][row] = va.w;
      float4 vw = *(const float4*)(W + (size_t)(n0 + row) * ldw + k0 + c4);
      Ws[c4 + 0][row] = vw.x; Ws[c4 + 1][row] = vw.y;
      Ws[c4 + 2][row] = vw.z; Ws[c4 + 3][row] = vw.w;
    }
    __syncthreads();
#pragma unroll
    for (int k = 0; k < 16; ++k) {
      float a[8], w[8];
      *(float4*)&a[0] = *(const float4*)&As[k][tm * 8];
      *(float4*)&a[4] = *(const float4*)&As[k][tm * 8 + 4];
      *(float4*)&w[0] = *(const float4*)&Ws[k][tn * 8];
      *(float4*)&w[4] = *(const float4*)&Ws[k][tn * 8 + 4];
#pragma unroll
      for (int i = 0; i < 8; ++i)
#pragma unroll
        for (int j = 0; j < 8; ++j) acc[i][j] = fmaf(a[i], w[j], acc[i][j]);
    }
    __syncthreads();
  }
#pragma unroll
  for (int i = 0; i < 8; ++i) {
    int m = m0 + tm * 8 + i;
    size_t rowoff = permuteBT ? ((size_t)((m & 31) * TT + (m >> 5))) * N
                              : (size_t)m * N;
#pragma unroll
    for (int jj = 0; jj < 2; ++jj) {
      int n = n0 + tn * 8 + jj * 4;
      float4 v;
      v.x = acc[i][jj * 4 + 0]; v.y = acc[i][jj * 4 + 1];
      v.z = acc[i][jj * 4 + 2]; v.w = acc[i][jj * 4 + 3];
      if (bias) { v.x += bias[n]; v.y += bias[n + 1];
                  v.z += bias[n + 2]; v.w += bias[n + 3]; }
      *(float4*)(C + rowoff + n) = v;
    }
  }
}

// ---------- recurrent skinny split-K GEMM ----------
// Cpart[ks][32][N] = A[32,1024(chunk ks)] @ W[N,1024]^T   (pure dot, no bias)
// Two independent GEMMs fused on blockIdx.z. Ntile=64, Ktile=64, 128 thr, 4x4.
__global__ __launch_bounds__(128) void k_gemm_rec(
    const float* __restrict__ A0, const float* __restrict__ W0, int ldw0,
    float* __restrict__ C0,
    const float* __restrict__ A1, const float* __restrict__ W1, int ldw1,
    float* __restrict__ C1, int N) {
  __shared__ float As[64][36];    // [k][m]
  __shared__ float Ws[64][68];    // [k][n]
  const int set = blockIdx.z;
  const float* A = set ? A1 : A0;
  const float* W = set ? W1 : W0;
  const int ldw  = set ? ldw1 : ldw0;
  float* C       = set ? C1 : C0;
  const int n0 = blockIdx.x * 64;
  const int kbeg = blockIdx.y * (HH / KS);
  const int t = threadIdx.x;
  const int tn = t & 15, tmg = t >> 4;   // 16 n-groups x 8 m-groups
  float acc[4][4] = {};
  for (int k0 = kbeg; k0 < kbeg + HH / KS; k0 += 64) {
#pragma unroll
    for (int qq = 0; qq < 4; ++qq) {
      int f = t + 128 * qq;              // 0..511 : A 32x64
      int row = f >> 4, c4 = (f & 15) << 2;
      float4 v = *(const float4*)(A + (size_t)row * HH + k0 + c4);
      As[c4 + 0][row] = v.x; As[c4 + 1][row] = v.y;
      As[c4 + 2][row] = v.z; As[c4 + 3][row] = v.w;
    }
#pragma unroll
    for (int qq = 0; qq < 8; ++qq) {
      int f = t + 128 * qq;              // 0..1023 : W 64x64
      int row = f >> 4, c4 = (f & 15) << 2;
      float4 v = *(const float4*)(W + (size_t)(n0 + row) * ldw + k0 + c4);
      Ws[c4 + 0][row] = v.x; Ws[c4 + 1][row] = v.y;
      Ws[c4 + 2][row] = v.z; Ws[c4 + 3][row] = v.w;
    }
    __syncthreads();
#pragma unroll
    for (int k = 0; k < 64; ++k) {
      float4 a = *(const float4*)&As[k][tmg << 2];
      float4 w = *(const float4*)&Ws[k][tn << 2];
      acc[0][0] = fmaf(a.x, w.x, acc[0][0]); acc[0][1] = fmaf(a.x, w.y, acc[0][1]);
      acc[0][2] = fmaf(a.x, w.z, acc[0][2]); acc[0][3] = fmaf(a.x, w.w, acc[0][3]);
      acc[1][0] = fmaf(a.y, w.x, acc[1][0]); acc[1][1] = fmaf(a.y, w.y, acc[1][1]);
      acc[1][2] = fmaf(a.y, w.z, acc[1][2]); acc[1][3] = fmaf(a.y, w.w, acc[1][3]);
      acc[2][0] = fmaf(a.z, w.x, acc[2][0]); acc[2][1] = fmaf(a.z, w.y, acc[2][1]);
      acc[2][2] = fmaf(a.z, w.z, acc[2][2]); acc[2][3] = fmaf(a.z, w.w, acc[2][3]);
      acc[3][0] = fmaf(a.w, w.x, acc[3][0]); acc[3][1] = fmaf(a.w, w.y, acc[3][1]);
      acc[3][2] = fmaf(a.w, w.z, acc[3][2]); acc[3][3] = fmaf(a.w, w.w, acc[3][3]);
    }
    __syncthreads();
  }
#pragma unroll
  for (int i = 0; i < 4; ++i) {
    int m = tmg * 4 + i;
    float4 v; v.x = acc[i][0]; v.y = acc[i][1]; v.z = acc[i][2]; v.w = acc[i][3];
    *(float4*)(C + ((size_t)blockIdx.y * BB + m) * N + n0 + tn * 4) = v;
  }
}

// ---------- attention scores (fuses q-partial reduction) ----------
// grid (B, S/8), 256 threads. scores[b,s] = sum_h tanh(q+keys)·wv, masked.
__global__ __launch_bounds__(256) void k_scores(
    const float* __restrict__ qpart, const float* __restrict__ keys,
    const float* __restrict__ wv, const int* __restrict__ vlen,
    float* __restrict__ scores) {
  __shared__ float qs[HH];
  __shared__ float red[4][8];
  const int b = blockIdx.x, sg = blockIdx.y;
  const int t = threadIdx.x;
  for (int h = t; h < HH; h += 256) {
    float s = 0;
#pragma unroll
    for (int p = 0; p < KS; ++p)
      s += qpart[(size_t)p * BB * HH + (size_t)b * HH + h];
    qs[h] = s;
  }
  __syncthreads();
  float acc[8] = {0, 0, 0, 0, 0, 0, 0, 0};
  const float* kbase = keys + ((size_t)b * SS + sg * 8) * HH;
  for (int h = t; h < HH; h += 256) {
    float qv = qs[h], wvv = wv[h];
#pragma unroll
    for (int ss = 0; ss < 8; ++ss)
      acc[ss] = fmaf(tanhf(qv + kbase[(size_t)ss * HH + h]), wvv, acc[ss]);
  }
  const int lane = t & 63, wid = t >> 6;
#pragma unroll
  for (int ss = 0; ss < 8; ++ss) {
    float r = acc[ss];
    for (int o = 32; o > 0; o >>= 1) r += __shfl_down(r, o);
    if (lane == 0) red[wid][ss] = r;
  }
  __syncthreads();
  if (t < 8) {
    float tot = red[0][t] + red[1][t] + red[2][t] + red[3][t];
    int s = sg * 8 + t;
    scores[b * SS + s] = (s < vlen[b]) ? tot : NEGV;
  }
}

// ---------- softmax + ctx ---------- grid (B, H/256), 256 threads
__global__ __launch_bounds__(256) void k_ctx(
    const float* __restrict__ scores, const float* __restrict__ enc,
    float* __restrict__ ctx) {
  __shared__ float sc[SS];
  const int b = blockIdx.x;
  const int t = threadIdx.x;
  const int h = blockIdx.y * 256 + t;
  if (t < SS) sc[t] = scores[b * SS + t];
  __syncthreads();
  float mx = sc[0];
  for (int s = 1; s < SS; ++s) mx = fmaxf(mx, sc[s]);
  float e = (t < SS) ? expf(sc[t] - mx) : 0.f;
  __syncthreads();
  if (t < SS) sc[t] = e;
  __syncthreads();
  float sum = 0;
  for (int s = 0; s < SS; ++s) sum += sc[s];
  float inv = 1.f / sum;
  float a = 0;
  const float* ep = enc + (size_t)b * SS * HH + h;
  for (int s = 0; s < SS; ++s) a = fmaf(sc[s], ep[(size_t)s * HH], a);
  ctx[b * HH + h] = a * inv;
}

// ---------- GRU elementwise (reduces split-K partials) ----------
__global__ __launch_bounds__(256) void k_gru(
    const float* __restrict__ gix, const float* __restrict__ giP,
    const float* __restrict__ ghP, const float* __restrict__ bih,
    const float* __restrict__ bhh, float* __restrict__ h,
    float* __restrict__ outrow) {
  const int idx = blockIdx.x * 256 + threadIdx.x;   // B*H
  const int b = idx >> 10, hh = idx & 1023;
  const size_t base3 = (size_t)b * H3;
  float ir = 0, iz = 0, inn = 0, hr = 0, hz = 0, hn = 0;
#pragma unroll
  for (int p = 0; p < KS; ++p) {
    const size_t pb = (size_t)p * BB * H3 + base3 + hh;
    ir += giP[pb]; iz += giP[pb + HH]; inn += giP[pb + 2 * HH];
    hr += ghP[pb]; hz += ghP[pb + HH]; hn += ghP[pb + 2 * HH];
  }
  if (gix) { ir += gix[base3 + hh]; iz += gix[base3 + HH + hh];
             inn += gix[base3 + 2 * HH + hh]; }
  if (bih) { ir += bih[hh]; iz += bih[HH + hh]; inn += bih[2 * HH + hh]; }
  hr += bhh[hh]; hz += bhh[HH + hh]; hn += bhh[2 * HH + hh];
  float r = 1.f / (1.f + expf(-(ir + hr)));
  float z = 1.f / (1.f + expf(-(iz + hz)));
  float n = tanhf(inn + r * hn);
  float hv = (1.f - z) * n + z * h[idx];
  h[idx] = hv;
  if (outrow) outrow[idx] = hv;
}

// ---------------------------------------------------------------------------
extern "C" void kernel_launch(void* const* d_in, const int* in_sizes, int n_in,
                              void* d_out, int out_size, void* d_ws,
                              size_t ws_size, hipStream_t stream) {
  const int*   X    = (const int*)  d_in[0];
  const float* enc  = (const float*)d_in[1];
  const float* hid  = (const float*)d_in[2];
  const int*   vlen = (const int*)  d_in[3];
  const float* emb  = (const float*)d_in[4];
  const float* Wq   = (const float*)d_in[5];
  const float* Wk   = (const float*)d_in[6];
  const float* wv   = (const float*)d_in[7];
  const float* Wih0 = (const float*)d_in[8];
  const float* Whh0 = (const float*)d_in[9];
  const float* bih0 = (const float*)d_in[10];
  const float* bhh0 = (const float*)d_in[11];
  const float* Wih1 = (const float*)d_in[12];
  const float* Whh1 = (const float*)d_in[13];
  const float* bih1 = (const float*)d_in[14];
  const float* bhh1 = (const float*)d_in[15];
  const float* Wout = (const float*)d_in[16];
  const float* bout = (const float*)d_in[17];
  float* out = (float*)d_out;

  float* ws = (float*)d_ws;                      // all sizes in floats
  float* keys   = ws;                            // 4096*1024   = 4194304
  float* gi0x   = keys   + (size_t)4194304;      // 2048*3072   = 6291456
  float* outs   = gi0x   + (size_t)6291456;      // 2048*1024   = 2097152
  float* xs     = outs   + (size_t)2097152;      // 2048*512    = 1048576
  float* h0     = xs     + (size_t)1048576;      // 32768
  float* h1     = h0     + 32768;                // 32768
  float* scores = h1     + 32768;                // 4096
  float* ctx    = scores + 4096;                 // 32768
  float* qpart  = ctx    + 32768;                // KS*32*1024  = 262144
  float* gicP   = qpart  + 262144;               // KS*32*3072  = 786432
  float* ghP0   = gicP   + 786432;
  float* giP1   = ghP0   + 786432;
  float* ghP1   = giP1   + 786432;               // end ~68.6 MB

  k_init_h<<<256, 256, 0, stream>>>(hid, h0, h1);
  k_gather<<<1024, 256, 0, stream>>>(X, emb, xs);
  // keys = enc @ Wk^T              [4096,1024] x [1024,1024]
  k_gemm_tiled<<<dim3(8, 32), 256, 0, stream>>>(enc, HH, Wk, HH, nullptr,
                                                keys, BB * SS, HH, HH, 0);
  // gi0x = xs @ W_ih0[:,H:]^T + b_ih0   [2048,512] x [3072,512]
  k_gemm_tiled<<<dim3(24, 16), 256, 0, stream>>>(xs, EE, Wih0 + HH, HH + EE,
                                                 bih0, gi0x, TT * BB, H3, EE, 0);

  for (int td = 0; td < TT; ++td) {
    // q partials = h1 @ Wq^T
    k_gemm_rec<<<dim3(16, KS, 1), 128, 0, stream>>>(h1, Wq, HH, qpart,
                                                    h1, Wq, HH, qpart, HH);
    k_scores<<<dim3(32, 16), 256, 0, stream>>>(qpart, keys, wv, vlen, scores);
    k_ctx<<<dim3(32, 4), 256, 0, stream>>>(scores, enc, ctx);
    // gi0c = ctx @ W_ih0[:,:H]^T ; gh0 = h0 @ W_hh0^T
    k_gemm_rec<<<dim3(48, KS, 2), 128, 0, stream>>>(ctx, Wih0, HH + EE, gicP,
                                                    h0, Whh0, HH, ghP0, H3);
    k_gru<<<128, 256, 0, stream>>>(gi0x + (size_t)td * BB * H3, gicP, ghP0,
                                   nullptr, bhh0, h0, nullptr);
    // gi1 = h0 @ W_ih1^T ; gh1 = h1 @ W_hh1^T
    k_gemm_rec<<<dim3(48, KS, 2), 128, 0, stream>>>(h0, Wih1, HH, giP1,
                                                    h1, Whh1, HH, ghP1, H3);
    k_gru<<<128, 256, 0, stream>>>(nullptr, giP1, ghP1, bih1, bhh1, h1,
                                   outs + (size_t)td * BB * HH);
  }
  // logits = outs @ W_out^T + b_out, permuted [t*B+b] -> [b,t]
  k_gemm_tiled<<<dim3(250, 16), 256, 0, stream>>>(outs, HH, Wout, HH, bout,
                                                  out, TT * BB, VV, HH, 1);
}